// Round 11
// baseline (125.090 us; speedup 1.0000x reference)
//
#include <hip/hip_runtime.h>

#define NUM_LABELS 1025
#define LSLOTS (2 * NUM_LABELS)            // [2][1025] u64 = 16.4 KB LDS
#define THREADS 1024
#define SL 512                             // K1 blocks (slices); 64 per batch
#define BPB (SL / 8)                       // 64 slices per batch
#define GPB 5                              // K2 label-groups per batch
#define LPG 205                            // labels per group (5*205 = 1025)
#define K2BLOCKS (8 * GPB)                 // 40
static constexpr int HW = 1024 * 1024;
static constexpr float LINE_THRESH = 63.75f;     // 255/4
static constexpr float QSCALE = 8.0f;            // fixed point 2^3
static constexpr float INVQ   = 0.125f;
typedef unsigned long long u64;
typedef unsigned int u32;

// K1 ablation family (r10 structure, verified absmax=0.0).
// MODE 0: real kernel (runs LAST; overwrites bins_g/a_g -> output unchanged).
// MODE 1: loads+encode+A-term, NO LDS atomics (keepalive sinks, no DCE).
// MODE 2: full instruction stream, synthetic uniform labels (t+j*257+q)&1023.
// All three write the same bins_g/a_g slices (full overwrite; V0 last wins).
template<int MODE>
__global__ __launch_bounds__(THREADS) void spx_k1t(
    const float* __restrict__ Is, const int* __restrict__ Ispp,
    const float* __restrict__ Il, u64* __restrict__ bins_g,
    float* __restrict__ a_g)
{
    __shared__ u64 bins[LSLOTS];
    const int t = threadIdx.x;
    for (int i = t; i < LSLOTS; i += THREADS) bins[i] = 0ull;
    __syncthreads();

    const int b   = blockIdx.x / BPB;
    const int blk = blockIdx.x % BPB;
    const long long planeI = (long long)b * HW;
    const long long chan0  = (long long)(b * 4) * HW;

    float a = 0.f;
    u32 sink = 0;
    const int QB = HW >> 2;                    // 262144 quads per batch
#pragma unroll 2
    for (int q = blk * THREADS + t; q < QB; q += BPB * THREADS) {
        const int pix = q << 2;

        const int4   lab4 = *(const int4*)(Ispp + planeI + pix);
        const float4 il4  = *(const float4*)(Il + planeI + pix);
        float4 ch[4];
#pragma unroll
        for (int c = 0; c < 4; ++c)
            ch[c] = *(const float4*)(Is + chan0 + (long long)c * HW + pix);

        const int*   lab = (const int*)&lab4;
        const float* il  = (const float*)&il4;
        const float* f0  = (const float*)&ch[0];
        const float* f1  = (const float*)&ch[1];
        const float* f2  = (const float*)&ch[2];
        const float* f3  = (const float*)&ch[3];

#pragma unroll
        for (int j = 0; j < 4; ++j) {
            const float v0 = f0[j], v1 = f1[j], v2 = f2[j], v3 = f3[j];
            const int q0 = __float2int_rn(v0 * QSCALE) + 64;
            const int q1 = __float2int_rn(v1 * QSCALE) + 64;
            const int q2 = __float2int_rn(v2 * QSCALE) + 64;
            const int q3 = __float2int_rn(v3 * QSCALE) + 64;
            const u64 enc = (u64)(u32)q0 | ((u64)(u32)q1 << 14)
                          | ((u64)(u32)q2 << 28) | ((u64)(u32)q3 << 42)
                          | (1ULL << 56);

            int L;
            if (MODE == 2) {
                L = (int)(((u32)t + (u32)j * 257u + (u32)q) & 1023u);
                sink ^= (u32)lab[j];             // keep the Ispp load live
            } else {
                L = lab[j];
            }

            if (MODE == 1) {
                // no atomics: keep lab/enc live via sink, keep branch+A-term
                sink ^= (u32)lab[j] ^ (u32)enc ^ (u32)(enc >> 32);
                if (il[j] > LINE_THRESH)
                    a += v0 * v0 + v1 * v1 + v2 * v2 + v3 * v3;
            } else {
                atomicAdd(&bins[L], enc);
                if (il[j] > LINE_THRESH) {
                    a += v0 * v0 + v1 * v1 + v2 * v2 + v3 * v3;
                } else {
                    atomicAdd(&bins[NUM_LABELS + L], enc);
                }
            }
        }
    }
    __syncthreads();

    // flush slice (identical in all modes; MODE0 runs last and wins)
    u64* dst = bins_g + (size_t)blockIdx.x * LSLOTS;
    for (int i = t; i < LSLOTS; i += THREADS) dst[i] = bins[i];

    if (MODE != 0) asm volatile("" :: "v"(sink));   // DCE guard (rule #17)

    // deterministic block reduce of A
#pragma unroll
    for (int off = 32; off >= 1; off >>= 1) a += __shfl_xor(a, off, 64);
    __shared__ float apart[THREADS / 64];
    if ((t & 63) == 0) apart[t >> 6] = a;
    __syncthreads();
    if (t == 0) {
        float s = 0.f;
#pragma unroll
        for (int w = 0; w < THREADS / 64; ++w) s += apart[w];
        a_g[blockIdx.x] = s;
    }
}

// K2: label-parallel, coalesced slice reduce (r10, verified) -> partial[40]
__global__ __launch_bounds__(256) void spx_k2(
    const u64* __restrict__ bins_g, float* __restrict__ partial)
{
    const int b = blockIdx.x / GPB;
    const int g = blockIdx.x % GPB;
    const int t = threadIdx.x;

    float c = 0.f;
    if (t < LPG) {
        const int lab = g * LPG + t;               // 0..1024
        float v[10];
#pragma unroll
        for (int j = 0; j < 10; ++j) v[j] = 0.f;

        const u64* base = bins_g + (size_t)b * BPB * LSLOTS;
#pragma unroll 4
        for (int k = 0; k < BPB; ++k) {
            const u64 va = base[(size_t)k * LSLOTS + lab];
            const u64 vm = base[(size_t)k * LSLOTS + NUM_LABELS + lab];

            const int n  = (int)(va >> 56);
            const int nb = n << 6;                 // 64*n bias
            v[0] += (float)((int)(va         & 0x3FFF) - nb) * INVQ;
            v[1] += (float)((int)((va >> 14) & 0x3FFF) - nb) * INVQ;
            v[2] += (float)((int)((va >> 28) & 0x3FFF) - nb) * INVQ;
            v[3] += (float)((int)((va >> 42) & 0x3FFF) - nb) * INVQ;
            v[4] += (float)n;

            const int m  = (int)(vm >> 56);
            const int mb = m << 6;
            v[5] += (float)((int)(vm         & 0x3FFF) - mb) * INVQ;
            v[6] += (float)((int)((vm >> 14) & 0x3FFF) - mb) * INVQ;
            v[7] += (float)((int)((vm >> 28) & 0x3FFF) - mb) * INVQ;
            v[8] += (float)((int)((vm >> 42) & 0x3FFF) - mb) * INVQ;
            v[9] += (float)m;
        }

        if (lab != 0) {
            const float inv = 1.f / fmaxf(v[4], 1.f);
            const float t3  = v[4] - v[9];
#pragma unroll
            for (int j = 0; j < 4; ++j) {
                const float m  = v[j] * inv;
                const float t2 = v[j] - v[5 + j];
                c += t3 * m * m - 2.f * m * t2;
            }
        }
    }

    __shared__ float red[256];
    red[t] = c;
    __syncthreads();
    for (int off = 128; off >= 1; off >>= 1) {
        if (t < off) red[t] += red[t + off];
        __syncthreads();
    }
    if (t == 0) partial[blockIdx.x] = red[0];
}

// K3: out = (sum(partial[0..39]) + sum(a_g[0..511])) / NPIX, deterministic
__global__ __launch_bounds__(1024) void spx_k3(
    const float* __restrict__ partial, const float* __restrict__ a_g,
    float* __restrict__ out)
{
    const int t = threadIdx.x;
    float s = (t < K2BLOCKS ? partial[t] : 0.f) + (t < SL ? a_g[t] : 0.f);
    __shared__ float red[1024];
    red[t] = s;
    __syncthreads();
    for (int off = 512; off >= 1; off >>= 1) {
        if (t < off) red[t] += red[t + off];
        __syncthreads();
    }
    if (t == 0) out[0] = red[0] / 8388608.0f;
}

extern "C" void kernel_launch(void* const* d_in, const int* in_sizes, int n_in,
                              void* d_out, int out_size, void* d_ws, size_t ws_size,
                              hipStream_t stream)
{
    const float* Is   = (const float*)d_in[0];
    const int*   Ispp = (const int*)d_in[1];
    const float* Il   = (const float*)d_in[2];
    float* out = (float*)d_out;

    u64*   bins_g  = (u64*)d_ws;                       // 512*2050*8 = 8.4 MB
    float* a_g     = (float*)(bins_g + (size_t)SL * LSLOTS);
    float* partial = a_g + SL;

    // Ablation dispatches (diagnostic): V1 = no atomics, V2 = uniform labels.
    // Both fully overwritten by the real V0 below -> output identical.
    spx_k1t<1><<<SL, THREADS, 0, stream>>>(Is, Ispp, Il, bins_g, a_g);
    spx_k1t<2><<<SL, THREADS, 0, stream>>>(Is, Ispp, Il, bins_g, a_g);
    // Real pipeline:
    spx_k1t<0><<<SL, THREADS, 0, stream>>>(Is, Ispp, Il, bins_g, a_g);
    spx_k2<<<K2BLOCKS, 256, 0, stream>>>(bins_g, partial);
    spx_k3<<<1, 1024, 0, stream>>>(partial, a_g, out);
}

// Round 12
// 65.244 us; speedup vs baseline: 1.9173x; 1.9173x over previous
//
#include <hip/hip_runtime.h>

#define NUM_LABELS 1025
#define LSLOTS (2 * NUM_LABELS)            // [2][1025] u64 = 16.4 KB LDS
#define THREADS 1024
#define SL 512                             // K1 blocks (slices); 64 per batch
#define BPB (SL / 8)                       // 64 slices per batch
#define GPB 5                              // K2 label-groups per batch
#define LPG 205                            // labels per group (5*205 = 1025)
#define K2BLOCKS (8 * GPB)                 // 40
static constexpr int HW = 1024 * 1024;
static constexpr float LINE_THRESH = 63.75f;     // 255/4
static constexpr float QSCALE = 8.0f;            // fixed point 2^3
static constexpr float INVQ   = 0.125f;
typedef unsigned long long u64;
typedef unsigned int u32;

// K1 (r10 verbatim, verified absmax=0.0, VGPR 28): one pass; each block
// serves ONE batch; label-only LDS u64 histogram; ONE u64 atomic per pixel:
//   bits [0:13] c0+64n | [14:27] c1+64n | [28:41] c2+64n | [42:55] c3+64n | [56:63] n
// slot[0][lab] = all pixels; slot[1][lab] = wl==0 subset (1.25 atomics/px avg).
// Ablation r11 verdict: atomics are hidden under the load stream (V1 no-atomic
// = 83.5us vs V0 95us profiled); K1 is at the effective memory ceiling.
__global__ __launch_bounds__(THREADS) void spx_k1(
    const float* __restrict__ Is, const int* __restrict__ Ispp,
    const float* __restrict__ Il, u64* __restrict__ bins_g,
    float* __restrict__ a_g)
{
    __shared__ u64 bins[LSLOTS];
    const int t = threadIdx.x;
    for (int i = t; i < LSLOTS; i += THREADS) bins[i] = 0ull;
    __syncthreads();

    const int b   = blockIdx.x / BPB;
    const int blk = blockIdx.x % BPB;
    const long long planeI = (long long)b * HW;
    const long long chan0  = (long long)(b * 4) * HW;

    float a = 0.f;
    const int QB = HW >> 2;                    // 262144 quads per batch
#pragma unroll 2
    for (int q = blk * THREADS + t; q < QB; q += BPB * THREADS) {
        const int pix = q << 2;

        const int4   lab4 = *(const int4*)(Ispp + planeI + pix);
        const float4 il4  = *(const float4*)(Il + planeI + pix);
        float4 ch[4];
#pragma unroll
        for (int c = 0; c < 4; ++c)
            ch[c] = *(const float4*)(Is + chan0 + (long long)c * HW + pix);

        const int*   lab = (const int*)&lab4;
        const float* il  = (const float*)&il4;
        const float* f0  = (const float*)&ch[0];
        const float* f1  = (const float*)&ch[1];
        const float* f2  = (const float*)&ch[2];
        const float* f3  = (const float*)&ch[3];

#pragma unroll
        for (int j = 0; j < 4; ++j) {
            const float v0 = f0[j], v1 = f1[j], v2 = f2[j], v3 = f3[j];
            const int q0 = __float2int_rn(v0 * QSCALE) + 64;
            const int q1 = __float2int_rn(v1 * QSCALE) + 64;
            const int q2 = __float2int_rn(v2 * QSCALE) + 64;
            const int q3 = __float2int_rn(v3 * QSCALE) + 64;
            const u64 enc = (u64)(u32)q0 | ((u64)(u32)q1 << 14)
                          | ((u64)(u32)q2 << 28) | ((u64)(u32)q3 << 42)
                          | (1ULL << 56);
            const int L = lab[j];
            atomicAdd(&bins[L], enc);
            if (il[j] > LINE_THRESH) {
                a += v0 * v0 + v1 * v1 + v2 * v2 + v3 * v3;
            } else {
                atomicAdd(&bins[NUM_LABELS + L], enc);
            }
        }
    }
    __syncthreads();

    // flush slice (coalesced u64 writes, 16.4 KB per block)
    u64* dst = bins_g + (size_t)blockIdx.x * LSLOTS;
    for (int i = t; i < LSLOTS; i += THREADS) dst[i] = bins[i];

    // deterministic block reduce of A
#pragma unroll
    for (int off = 32; off >= 1; off >>= 1) a += __shfl_xor(a, off, 64);
    __shared__ float apart[THREADS / 64];
    if ((t & 63) == 0) apart[t >> 6] = a;
    __syncthreads();
    if (t == 0) {
        float s = 0.f;
#pragma unroll
        for (int w = 0; w < THREADS / 64; ++w) s += apart[w];
        a_g[blockIdx.x] = s;
    }
}

// K2f (fused K2+K3): label-parallel coalesced slice reduce (r10 K2, verified)
// -> partial[40]; ticket-based last block (r8-proven pattern, but only 40
// blocks -> ~2.6us worst-case serialization) sums partial (agent-scope atomic
// loads) + a_g (written by previous kernel -> visible) in fixed order.
__global__ __launch_bounds__(256) void spx_k2f(
    const u64* __restrict__ bins_g, const float* __restrict__ a_g,
    float* __restrict__ partial, u32* __restrict__ ticket,
    float* __restrict__ out)
{
    const int b = blockIdx.x / GPB;
    const int g = blockIdx.x % GPB;
    const int t = threadIdx.x;

    float c = 0.f;
    if (t < LPG) {
        const int lab = g * LPG + t;               // 0..1024
        float v[10];
#pragma unroll
        for (int j = 0; j < 10; ++j) v[j] = 0.f;

        const u64* base = bins_g + (size_t)b * BPB * LSLOTS;
#pragma unroll 4
        for (int k = 0; k < BPB; ++k) {
            const u64 va = base[(size_t)k * LSLOTS + lab];
            const u64 vm = base[(size_t)k * LSLOTS + NUM_LABELS + lab];

            const int n  = (int)(va >> 56);
            const int nb = n << 6;                 // 64*n bias
            v[0] += (float)((int)(va         & 0x3FFF) - nb) * INVQ;
            v[1] += (float)((int)((va >> 14) & 0x3FFF) - nb) * INVQ;
            v[2] += (float)((int)((va >> 28) & 0x3FFF) - nb) * INVQ;
            v[3] += (float)((int)((va >> 42) & 0x3FFF) - nb) * INVQ;
            v[4] += (float)n;

            const int m  = (int)(vm >> 56);
            const int mb = m << 6;
            v[5] += (float)((int)(vm         & 0x3FFF) - mb) * INVQ;
            v[6] += (float)((int)((vm >> 14) & 0x3FFF) - mb) * INVQ;
            v[7] += (float)((int)((vm >> 28) & 0x3FFF) - mb) * INVQ;
            v[8] += (float)((int)((vm >> 42) & 0x3FFF) - mb) * INVQ;
            v[9] += (float)m;
        }

        if (lab != 0) {
            const float inv = 1.f / fmaxf(v[4], 1.f);
            const float t3  = v[4] - v[9];
#pragma unroll
            for (int j = 0; j < 4; ++j) {
                const float m  = v[j] * inv;
                const float t2 = v[j] - v[5 + j];
                c += t3 * m * m - 2.f * m * t2;
            }
        }
    }

    __shared__ float red[256];
    red[t] = c;
    __syncthreads();
    for (int off = 128; off >= 1; off >>= 1) {
        if (t < off) red[t] += red[t + off];
        __syncthreads();
    }

    __shared__ u32 lastflag;
    if (t == 0) {
        partial[blockIdx.x] = red[0];
        __threadfence();                            // device-scope publish
        const u32 old = atomicAdd(ticket, 1u);
        lastflag = (old == (u32)(K2BLOCKS - 1));
    }
    __syncthreads();

    if (lastflag) {
        float s = 0.f;
        for (int i = t; i < K2BLOCKS; i += 256)     // fixed per-thread order
            s += __hip_atomic_load(&partial[i], __ATOMIC_RELAXED,
                                   __HIP_MEMORY_SCOPE_AGENT);
        for (int i = t; i < SL; i += 256) s += a_g[i];
        red[t] = s;
        __syncthreads();
        for (int off = 128; off >= 1; off >>= 1) {
            if (t < off) red[t] += red[t + off];
            __syncthreads();
        }
        if (t == 0) out[0] = red[0] / 8388608.0f;
    }
}

extern "C" void kernel_launch(void* const* d_in, const int* in_sizes, int n_in,
                              void* d_out, int out_size, void* d_ws, size_t ws_size,
                              hipStream_t stream)
{
    const float* Is   = (const float*)d_in[0];
    const int*   Ispp = (const int*)d_in[1];
    const float* Il   = (const float*)d_in[2];
    float* out = (float*)d_out;

    u64*   bins_g  = (u64*)d_ws;                       // 512*2050*8 = 8.4 MB
    float* a_g     = (float*)(bins_g + (size_t)SL * LSLOTS);
    float* partial = a_g + SL;
    u32*   ticket  = (u32*)(partial + K2BLOCKS);

    hipMemsetAsync(ticket, 0, sizeof(u32), stream);
    spx_k1<<<SL, THREADS, 0, stream>>>(Is, Ispp, Il, bins_g, a_g);
    spx_k2f<<<K2BLOCKS, 256, 0, stream>>>(bins_g, a_g, partial, ticket, out);
}

// Round 13
// 59.932 us; speedup vs baseline: 2.0872x; 1.0886x over previous
//
#include <hip/hip_runtime.h>

#define NUM_LABELS 1025
#define LSLOTS (2 * NUM_LABELS)            // [2][1025] u64 = 16.4 KB LDS
#define THREADS 1024
#define SL 512                             // K1 blocks (slices); 64 per batch
#define BPB (SL / 8)                       // 64 slices per batch
#define GPB 5                              // K2 label-groups per batch
#define LPG 205                            // labels per group (5*205 = 1025)
#define K2BLOCKS (8 * GPB)                 // 40
static constexpr int HW = 1024 * 1024;
static constexpr float LINE_THRESH = 63.75f;     // 255/4
static constexpr float QSCALE = 8.0f;            // fixed point 2^3
static constexpr float INVQ   = 0.125f;
typedef unsigned long long u64;
typedef unsigned int u32;

// K1 (r10 verbatim, verified absmax=0.0, VGPR 28) + ticket zeroing.
// One pass; each block serves ONE batch; label-only LDS u64 histogram;
// ONE u64 atomic per pixel:
//   bits [0:13] c0+64n | [14:27] c1+64n | [28:41] c2+64n | [42:55] c3+64n | [56:63] n
// slot[0][lab] = all pixels; slot[1][lab] = wl==0 subset (1.25 atomics/px avg).
// r11 ablation: atomics hidden under the load stream; K1 is load-stream-bound
// at ~5.1 TB/s effective (218 MB, ~half L3-served).
__global__ __launch_bounds__(THREADS) void spx_k1(
    const float* __restrict__ Is, const int* __restrict__ Ispp,
    const float* __restrict__ Il, u64* __restrict__ bins_g,
    float* __restrict__ a_g, u32* __restrict__ ticket)
{
    __shared__ u64 bins[LSLOTS];
    const int t = threadIdx.x;
    if (blockIdx.x == 0 && t == 0) *ticket = 0u;   // K1 completes before K2f
    for (int i = t; i < LSLOTS; i += THREADS) bins[i] = 0ull;
    __syncthreads();

    const int b   = blockIdx.x / BPB;
    const int blk = blockIdx.x % BPB;
    const long long planeI = (long long)b * HW;
    const long long chan0  = (long long)(b * 4) * HW;

    float a = 0.f;
    const int QB = HW >> 2;                    // 262144 quads per batch
#pragma unroll 2
    for (int q = blk * THREADS + t; q < QB; q += BPB * THREADS) {
        const int pix = q << 2;

        const int4   lab4 = *(const int4*)(Ispp + planeI + pix);
        const float4 il4  = *(const float4*)(Il + planeI + pix);
        float4 ch[4];
#pragma unroll
        for (int c = 0; c < 4; ++c)
            ch[c] = *(const float4*)(Is + chan0 + (long long)c * HW + pix);

        const int*   lab = (const int*)&lab4;
        const float* il  = (const float*)&il4;
        const float* f0  = (const float*)&ch[0];
        const float* f1  = (const float*)&ch[1];
        const float* f2  = (const float*)&ch[2];
        const float* f3  = (const float*)&ch[3];

#pragma unroll
        for (int j = 0; j < 4; ++j) {
            const float v0 = f0[j], v1 = f1[j], v2 = f2[j], v3 = f3[j];
            const int q0 = __float2int_rn(v0 * QSCALE) + 64;
            const int q1 = __float2int_rn(v1 * QSCALE) + 64;
            const int q2 = __float2int_rn(v2 * QSCALE) + 64;
            const int q3 = __float2int_rn(v3 * QSCALE) + 64;
            const u64 enc = (u64)(u32)q0 | ((u64)(u32)q1 << 14)
                          | ((u64)(u32)q2 << 28) | ((u64)(u32)q3 << 42)
                          | (1ULL << 56);
            const int L = lab[j];
            atomicAdd(&bins[L], enc);
            if (il[j] > LINE_THRESH) {
                a += v0 * v0 + v1 * v1 + v2 * v2 + v3 * v3;
            } else {
                atomicAdd(&bins[NUM_LABELS + L], enc);
            }
        }
    }
    __syncthreads();

    // flush slice (coalesced u64 writes, 16.4 KB per block)
    u64* dst = bins_g + (size_t)blockIdx.x * LSLOTS;
    for (int i = t; i < LSLOTS; i += THREADS) dst[i] = bins[i];

    // deterministic block reduce of A
#pragma unroll
    for (int off = 32; off >= 1; off >>= 1) a += __shfl_xor(a, off, 64);
    __shared__ float apart[THREADS / 64];
    if ((t & 63) == 0) apart[t >> 6] = a;
    __syncthreads();
    if (t == 0) {
        float s = 0.f;
#pragma unroll
        for (int w = 0; w < THREADS / 64; ++w) s += apart[w];
        a_g[blockIdx.x] = s;
    }
}

// K2f (r12's fused tail, verified absmax=0.0): label-parallel coalesced slice
// reduce -> partial[40]; ticket-based last block (only 40 increments) sums
// partial (agent-scope atomic loads) + a_g in fixed order, divides, writes out.
__global__ __launch_bounds__(256) void spx_k2f(
    const u64* __restrict__ bins_g, const float* __restrict__ a_g,
    float* __restrict__ partial, u32* __restrict__ ticket,
    float* __restrict__ out)
{
    const int b = blockIdx.x / GPB;
    const int g = blockIdx.x % GPB;
    const int t = threadIdx.x;

    float c = 0.f;
    if (t < LPG) {
        const int lab = g * LPG + t;               // 0..1024
        float v[10];
#pragma unroll
        for (int j = 0; j < 10; ++j) v[j] = 0.f;

        const u64* base = bins_g + (size_t)b * BPB * LSLOTS;
#pragma unroll 4
        for (int k = 0; k < BPB; ++k) {
            const u64 va = base[(size_t)k * LSLOTS + lab];
            const u64 vm = base[(size_t)k * LSLOTS + NUM_LABELS + lab];

            const int n  = (int)(va >> 56);
            const int nb = n << 6;                 // 64*n bias
            v[0] += (float)((int)(va         & 0x3FFF) - nb) * INVQ;
            v[1] += (float)((int)((va >> 14) & 0x3FFF) - nb) * INVQ;
            v[2] += (float)((int)((va >> 28) & 0x3FFF) - nb) * INVQ;
            v[3] += (float)((int)((va >> 42) & 0x3FFF) - nb) * INVQ;
            v[4] += (float)n;

            const int m  = (int)(vm >> 56);
            const int mb = m << 6;
            v[5] += (float)((int)(vm         & 0x3FFF) - mb) * INVQ;
            v[6] += (float)((int)((vm >> 14) & 0x3FFF) - mb) * INVQ;
            v[7] += (float)((int)((vm >> 28) & 0x3FFF) - mb) * INVQ;
            v[8] += (float)((int)((vm >> 42) & 0x3FFF) - mb) * INVQ;
            v[9] += (float)m;
        }

        if (lab != 0) {
            const float inv = 1.f / fmaxf(v[4], 1.f);
            const float t3  = v[4] - v[9];
#pragma unroll
            for (int j = 0; j < 4; ++j) {
                const float m  = v[j] * inv;
                const float t2 = v[j] - v[5 + j];
                c += t3 * m * m - 2.f * m * t2;
            }
        }
    }

    __shared__ float red[256];
    red[t] = c;
    __syncthreads();
    for (int off = 128; off >= 1; off >>= 1) {
        if (t < off) red[t] += red[t + off];
        __syncthreads();
    }

    __shared__ u32 lastflag;
    if (t == 0) {
        partial[blockIdx.x] = red[0];
        __threadfence();                            // device-scope publish
        const u32 old = atomicAdd(ticket, 1u);
        lastflag = (old == (u32)(K2BLOCKS - 1));
    }
    __syncthreads();

    if (lastflag) {
        float s = 0.f;
        for (int i = t; i < K2BLOCKS; i += 256)     // fixed per-thread order
            s += __hip_atomic_load(&partial[i], __ATOMIC_RELAXED,
                                   __HIP_MEMORY_SCOPE_AGENT);
        for (int i = t; i < SL; i += 256) s += a_g[i];
        red[t] = s;
        __syncthreads();
        for (int off = 128; off >= 1; off >>= 1) {
            if (t < off) red[t] += red[t + off];
            __syncthreads();
        }
        if (t == 0) out[0] = red[0] / 8388608.0f;
    }
}

extern "C" void kernel_launch(void* const* d_in, const int* in_sizes, int n_in,
                              void* d_out, int out_size, void* d_ws, size_t ws_size,
                              hipStream_t stream)
{
    const float* Is   = (const float*)d_in[0];
    const int*   Ispp = (const int*)d_in[1];
    const float* Il   = (const float*)d_in[2];
    float* out = (float*)d_out;

    u64*   bins_g  = (u64*)d_ws;                       // 512*2050*8 = 8.4 MB
    float* a_g     = (float*)(bins_g + (size_t)SL * LSLOTS);
    float* partial = a_g + SL;
    u32*   ticket  = (u32*)(partial + K2BLOCKS);

    spx_k1<<<SL, THREADS, 0, stream>>>(Is, Ispp, Il, bins_g, a_g, ticket);
    spx_k2f<<<K2BLOCKS, 256, 0, stream>>>(bins_g, a_g, partial, ticket, out);
}

// Round 14
// 56.213 us; speedup vs baseline: 2.2253x; 1.0662x over previous
//
#include <hip/hip_runtime.h>

#define NUM_LABELS 1025
#define STRIDE 9                           // LDS dwords per label; gcd(9,32)=1 spreads banks
#define NBIN (NUM_LABELS * STRIDE)         // 9225 dwords = 36.9 KB LDS per block
#define GROUP 8                            // compact dwords per label in global slices
static constexpr int HW = 1024 * 1024;
static constexpr int NBATCH = 8;
static constexpr float LINE_THRESH = 63.75f;     // 255/4
static constexpr int NSEG = NBATCH * NUM_LABELS; // 8200
static constexpr float QSCALE = 16384.0f;        // 2^14 fixed point
static constexpr float INVQ   = 1.0f / 16384.0f;
typedef unsigned int u32;

// Best-measured configuration (r5: 55.6 us, absmax 0.0). Session summary:
// - f32 LDS atomics are CAS-emulated on gfx950 -> int fixed-point (r2->r3: 282->56us)
// - K1 is load-stream-bound: r11 keepalive ablation showed removing ALL histogram
//   atomics saves only ~12%; every atomic-count/occupancy/MLP lever was null.
// - u32 stride-9 histogram (this) consistently 3-6% faster than u64-packed.
// - global single-line atomics are catastrophic (r4: +150us, r8: +135us).
// K1: one pass; each block serves ONE batch; label-only LDS u32 histogram.
//   bins[lab*9 + 0..3] : unmasked fixed-point sums; +0 embeds count<<24
//   bins[lab*9 + 4..7] : wl==0 subset sums;         +4 embeds mcount<<24
// a = sum over wl==1 pixels of sum_c x^2 (f32, deterministic block reduce).
__global__ __launch_bounds__(1024) void spx_k1(
    const float* __restrict__ Is, const int* __restrict__ Ispp,
    const float* __restrict__ Il, int* __restrict__ bins_g,
    float* __restrict__ a_g, int bpb)
{
    __shared__ int bins[NBIN];
    const int t = threadIdx.x;
    for (int i = t; i < NBIN; i += 1024) bins[i] = 0;
    __syncthreads();

    const int b   = blockIdx.x / bpb;
    const int blk = blockIdx.x % bpb;
    const long long planeI = (long long)b * HW;
    const long long chan0  = (long long)(b * 4) * HW;

    float a = 0.f;
    const int QB = HW >> 2;                    // 262144 quads per batch
#pragma unroll 2
    for (int q = blk * 1024 + t; q < QB; q += bpb * 1024) {
        const int pix = q << 2;

        const int4   lab4 = *(const int4*)(Ispp + planeI + pix);
        const float4 il4  = *(const float4*)(Il + planeI + pix);
        float4 ch[4];
#pragma unroll
        for (int c = 0; c < 4; ++c)
            ch[c] = *(const float4*)(Is + chan0 + (long long)c * HW + pix);

        const int*   lab = (const int*)&lab4;
        const float* il  = (const float*)&il4;
        const float* f0  = (const float*)&ch[0];
        const float* f1  = (const float*)&ch[1];
        const float* f2  = (const float*)&ch[2];
        const float* f3  = (const float*)&ch[3];

#pragma unroll
        for (int j = 0; j < 4; ++j) {
            const float v0 = f0[j], v1 = f1[j], v2 = f2[j], v3 = f3[j];
            const int base = lab[j] * STRIDE;
            const int q0 = __float2int_rn(v0 * QSCALE) + (1 << 24);
            const int q1 = __float2int_rn(v1 * QSCALE);
            const int q2 = __float2int_rn(v2 * QSCALE);
            const int q3 = __float2int_rn(v3 * QSCALE);
            atomicAdd(&bins[base + 0], q0);
            atomicAdd(&bins[base + 1], q1);
            atomicAdd(&bins[base + 2], q2);
            atomicAdd(&bins[base + 3], q3);
            if (il[j] > LINE_THRESH) {
                a += v0 * v0 + v1 * v1 + v2 * v2 + v3 * v3;
            } else {
                atomicAdd(&bins[base + 4], q0);
                atomicAdd(&bins[base + 5], q1);
                atomicAdd(&bins[base + 6], q2);
                atomicAdd(&bins[base + 7], q3);
            }
        }
    }
    __syncthreads();

    // compact flush: 8 dwords per label (coalesced global writes)
    int* dst = bins_g + (size_t)blockIdx.x * (NUM_LABELS * GROUP);
    for (int i = t; i < NUM_LABELS * GROUP; i += 1024)
        dst[i] = bins[(i >> 3) * STRIDE + (i & 7)];

    // deterministic block reduce of A
#pragma unroll
    for (int off = 32; off >= 1; off >>= 1) a += __shfl_xor(a, off, 64);
    __shared__ float apart[16];
    if ((t & 63) == 0) apart[t >> 6] = a;
    __syncthreads();
    if (t == 0) {
        float s = 0.f;
#pragma unroll
        for (int w = 0; w < 16; ++w) s += apart[w];
        a_g[blockIdx.x] = s;
    }
}

// K2: per segment, decode+reduce the batch's slices, emit correction:
//   corr_s = sum_c ( T3*m_c^2 - 2*m_c*T2_c ),  m = S/N, T2 = S-U, T3 = N-M
__global__ __launch_bounds__(256) void spx_k2(
    const int* __restrict__ bins_g, int bpb, float* __restrict__ corr)
{
    const int lane = threadIdx.x & 63;
    const int s = blockIdx.x * 4 + (threadIdx.x >> 6);   // NSEG = 2050*4
    const int b   = s / NUM_LABELS;
    const int lab = s % NUM_LABELS;

    // v: S0..S3, N, U0..U3, M
    float v[10];
#pragma unroll
    for (int j = 0; j < 10; ++j) v[j] = 0.f;

    for (int k = lane; k < bpb; k += 64) {
        const int* p = bins_g + (size_t)(b * bpb + k) * (NUM_LABELS * GROUP)
                     + lab * GROUP;
        const int4 wa = *(const int4*)(p);
        const int4 wb = *(const int4*)(p + 4);

        const u32 cN = ((u32)(wa.x + (1 << 23))) >> 24;
        const int s0 = wa.x - (int)(cN << 24);
        const u32 cM = ((u32)(wb.x + (1 << 23))) >> 24;
        const int u0 = wb.x - (int)(cM << 24);

        v[0] += (float)s0   * INVQ;
        v[1] += (float)wa.y * INVQ;
        v[2] += (float)wa.z * INVQ;
        v[3] += (float)wa.w * INVQ;
        v[4] += (float)cN;
        v[5] += (float)u0   * INVQ;
        v[6] += (float)wb.y * INVQ;
        v[7] += (float)wb.z * INVQ;
        v[8] += (float)wb.w * INVQ;
        v[9] += (float)cM;
    }
#pragma unroll
    for (int off = 32; off >= 1; off >>= 1) {
#pragma unroll
        for (int j = 0; j < 10; ++j) v[j] += __shfl_xor(v[j], off, 64);
    }

    if (lane == 0) {
        float c = 0.f;
        if (lab != 0) {
            const float inv = 1.f / fmaxf(v[4], 1.f);
            const float t3  = v[4] - v[9];
#pragma unroll
            for (int j = 0; j < 4; ++j) {
                const float m  = v[j] * inv;
                const float t2 = v[j] - v[5 + j];
                c += t3 * m * m - 2.f * m * t2;
            }
        }
        corr[s] = c;
    }
}

// K3: out = (sum(corr) + sum(A partials)) / NPIX, deterministic
__global__ __launch_bounds__(1024) void spx_k3(
    const float* __restrict__ corr, const float* __restrict__ a_g, int SL,
    float* __restrict__ out)
{
    __shared__ float red[1024];
    float s = 0.f;
    for (int i = threadIdx.x; i < NSEG; i += 1024) s += corr[i];
    for (int i = threadIdx.x; i < SL;   i += 1024) s += a_g[i];
    red[threadIdx.x] = s;
    __syncthreads();
    for (int off = 512; off >= 1; off >>= 1) {
        if (threadIdx.x < (unsigned)off) red[threadIdx.x] += red[threadIdx.x + off];
        __syncthreads();
    }
    if (threadIdx.x == 0) out[0] = red[0] / 8388608.0f;
}

extern "C" void kernel_launch(void* const* d_in, const int* in_sizes, int n_in,
                              void* d_out, int out_size, void* d_ws, size_t ws_size,
                              hipStream_t stream)
{
    const float* Is   = (const float*)d_in[0];
    const int*   Ispp = (const int*)d_in[1];
    const float* Il   = (const float*)d_in[2];
    float* out = (float*)d_out;

    int SL = 512;                       // K1 blocks (slices); multiple of 8
    while (SL > 8 &&
           ((size_t)SL * NUM_LABELS * GROUP * 4 + (size_t)SL * 4
            + (size_t)NSEG * 4) > ws_size)
        SL >>= 1;
    const int bpb = SL / NBATCH;

    int*   bins_g = (int*)d_ws;
    float* a_g    = (float*)(bins_g + (size_t)SL * NUM_LABELS * GROUP);
    float* corr   = a_g + SL;

    spx_k1<<<SL, 1024, 0, stream>>>(Is, Ispp, Il, bins_g, a_g, bpb);
    spx_k2<<<NSEG / 4, 256, 0, stream>>>(bins_g, bpb, corr);
    spx_k3<<<1, 1024, 0, stream>>>(corr, a_g, SL, out);
}